// Round 1
// baseline (890.604 us; speedup 1.0000x reference)
//
#include <hip/hip_runtime.h>
#include <math.h>

#define NH 12
#define DMODEL 768
#define DHEAD 64
#define BATCH 16
#define SEQ 512
#define NTOK (BATCH*SEQ)   // 8192
#define ATTN_SCALE 0.125f
#define LN_EPS 1e-3f

// ---------------------------------------------------------------------------
// Kernel 1: fused QKV projection.  out = x @ W + b, scattered to [B,H,L,DH].
// 64x64 output tile per block, 256 threads, 4x4 micro-tile per thread, BK=16.
// ---------------------------------------------------------------------------
__global__ __launch_bounds__(256) void gemm_qkv_kernel(
    const float* __restrict__ x,
    const float* __restrict__ W0, const float* __restrict__ W1, const float* __restrict__ W2,
    const float* __restrict__ b0, const float* __restrict__ b1, const float* __restrict__ b2,
    float* __restrict__ out0, float* __restrict__ out1, float* __restrict__ out2)
{
    const int zz = blockIdx.z;
    const float* W    = (zz == 0) ? W0 : (zz == 1) ? W1 : W2;
    const float* bias = (zz == 0) ? b0 : (zz == 1) ? b1 : b2;
    float* out        = (zz == 0) ? out0 : (zz == 1) ? out1 : out2;

    __shared__ float As[16][68];   // A^T tile (k-major), pad 68 -> conflict-free row reads
    __shared__ float Bs[16][64];   // B tile

    const int tid = threadIdx.x;
    const int tx = tid & 15, ty = tid >> 4;
    const int m0 = blockIdx.x * 64;
    const int n0 = blockIdx.y * 64;

    float acc[4][4] = {};

    for (int k0 = 0; k0 < DMODEL; k0 += 16) {
        {   // load A tile: rows m0..m0+63, cols k0..k0+15 (store transposed)
            int r = tid >> 4;     // 0..15
            int c = tid & 15;     // 0..15
            #pragma unroll
            for (int i = 0; i < 4; ++i) {
                int row = r + 16 * i;
                As[c][row] = x[(size_t)(m0 + row) * DMODEL + k0 + c];
            }
        }
        {   // load B tile: rows k0..k0+15, cols n0..n0+63
            int c  = tid & 63;
            int r0 = tid >> 6;    // 0..3
            #pragma unroll
            for (int i = 0; i < 4; ++i) {
                int kk = r0 + 4 * i;
                Bs[kk][c] = W[(size_t)(k0 + kk) * DMODEL + n0 + c];
            }
        }
        __syncthreads();
        #pragma unroll
        for (int kk = 0; kk < 16; ++kk) {
            float a[4], b[4];
            #pragma unroll
            for (int i = 0; i < 4; ++i) a[i] = As[kk][ty * 4 + i];
            #pragma unroll
            for (int j = 0; j < 4; ++j) b[j] = Bs[kk][tx * 4 + j];
            #pragma unroll
            for (int i = 0; i < 4; ++i)
                #pragma unroll
                for (int j = 0; j < 4; ++j)
                    acc[i][j] += a[i] * b[j];
        }
        __syncthreads();
    }

    // epilogue: add bias, scatter to [B, H, L, DH]
    #pragma unroll
    for (int i = 0; i < 4; ++i) {
        int t  = m0 + ty * 4 + i;
        int bi = t >> 9;          // /512
        int l  = t & 511;
        #pragma unroll
        for (int j = 0; j < 4; ++j) {
            int o  = n0 + tx * 4 + j;
            int h  = o >> 6;
            int dh = o & 63;
            out[(size_t)((bi * NH + h) * SEQ + l) * DHEAD + dh] = acc[i][j] + bias[o];
        }
    }
}

// ---------------------------------------------------------------------------
// Kernel 2: flash-style attention.  One block per (b, h, 64-query tile).
// Online softmax over key tiles of 64.  ctx written in [B, L, D] layout.
// ---------------------------------------------------------------------------
__global__ __launch_bounds__(256) void attn_kernel(
    const float* __restrict__ q, const float* __restrict__ k, const float* __restrict__ v,
    const int* __restrict__ mask, float* __restrict__ ctx)
{
    __shared__ float Qs[64][65];
    __shared__ float Ks[64][65];
    __shared__ float Vs[64][65];
    __shared__ float Ps[64][65];
    __shared__ float red[64][17];
    __shared__ float mS[64], lS[64], alphaS[64], maskS[64];

    const int tid = threadIdx.x;
    const int tx = tid & 15, ty = tid >> 4;
    const int q0 = blockIdx.x * 64;
    const int h  = blockIdx.y;
    const int b  = blockIdx.z;

    const float* qp = q + (size_t)((b * NH + h) * SEQ + q0) * DHEAD;
    const float* kp = k + (size_t)((b * NH + h) * SEQ) * DHEAD;
    const float* vp = v + (size_t)((b * NH + h) * SEQ) * DHEAD;

    // load Q tile (64x64)
    #pragma unroll
    for (int i = 0; i < 16; ++i) {
        int idx = tid + 256 * i;
        Qs[idx >> 6][idx & 63] = qp[idx];
    }
    if (tid < 64) { mS[tid] = -1e30f; lS[tid] = 0.f; }

    float o_acc[4][4] = {};

    for (int kt = 0; kt < SEQ; kt += 64) {
        __syncthreads();   // protects Ks/Vs/Ps reuse + initial Q/m/l visibility
        #pragma unroll
        for (int i = 0; i < 16; ++i) {
            int idx = tid + 256 * i;
            Ks[idx >> 6][idx & 63] = kp[(size_t)kt * DHEAD + idx];
            Vs[idx >> 6][idx & 63] = vp[(size_t)kt * DHEAD + idx];
        }
        if (tid < 64) maskS[tid] = (mask[b * SEQ + kt + tid] > 0) ? 0.f : -1e9f;
        __syncthreads();

        // S = Q K^T * scale + mask
        float s[4][4] = {};
        for (int kk = 0; kk < 64; ++kk) {
            float a[4], bb[4];
            #pragma unroll
            for (int i = 0; i < 4; ++i) a[i] = Qs[ty * 4 + i][kk];
            #pragma unroll
            for (int j = 0; j < 4; ++j) bb[j] = Ks[tx * 4 + j][kk];
            #pragma unroll
            for (int i = 0; i < 4; ++i)
                #pragma unroll
                for (int j = 0; j < 4; ++j)
                    s[i][j] += a[i] * bb[j];
        }
        #pragma unroll
        for (int i = 0; i < 4; ++i)
            #pragma unroll
            for (int j = 0; j < 4; ++j)
                s[i][j] = s[i][j] * ATTN_SCALE + maskS[tx * 4 + j];

        // per-row max (partial across the 16 tx threads)
        #pragma unroll
        for (int i = 0; i < 4; ++i) {
            float rm = fmaxf(fmaxf(s[i][0], s[i][1]), fmaxf(s[i][2], s[i][3]));
            red[ty * 4 + i][tx] = rm;
        }
        __syncthreads();
        if (tid < 64) {
            float m_old = mS[tid];
            float m_new = m_old;
            #pragma unroll
            for (int t2 = 0; t2 < 16; ++t2) m_new = fmaxf(m_new, red[tid][t2]);
            mS[tid] = m_new;
            alphaS[tid] = __expf(m_old - m_new);
        }
        __syncthreads();

        // P = exp(S - m), partial row sums, stage P in LDS
        #pragma unroll
        for (int i = 0; i < 4; ++i) {
            int r = ty * 4 + i;
            float mnew = mS[r];
            float rs = 0.f;
            #pragma unroll
            for (int j = 0; j < 4; ++j) {
                float p = __expf(s[i][j] - mnew);
                Ps[r][tx * 4 + j] = p;
                rs += p;
            }
            red[r][tx] = rs;
        }
        __syncthreads();
        if (tid < 64) {
            float ls = 0.f;
            #pragma unroll
            for (int t2 = 0; t2 < 16; ++t2) ls += red[tid][t2];
            lS[tid] = lS[tid] * alphaS[tid] + ls;
        }

        // O = O*alpha + P @ V
        #pragma unroll
        for (int i = 0; i < 4; ++i) {
            float al = alphaS[ty * 4 + i];
            #pragma unroll
            for (int j = 0; j < 4; ++j) o_acc[i][j] *= al;
        }
        for (int c = 0; c < 64; ++c) {
            float pv[4], vv[4];
            #pragma unroll
            for (int i = 0; i < 4; ++i) pv[i] = Ps[ty * 4 + i][c];
            #pragma unroll
            for (int j = 0; j < 4; ++j) vv[j] = Vs[c][tx * 4 + j];
            #pragma unroll
            for (int i = 0; i < 4; ++i)
                #pragma unroll
                for (int j = 0; j < 4; ++j)
                    o_acc[i][j] += pv[i] * vv[j];
        }
    }
    __syncthreads();  // lS final update visibility

    // ctx[b, l, h*64+d] = O / l
    #pragma unroll
    for (int i = 0; i < 4; ++i) {
        int r = ty * 4 + i;
        float inv = 1.f / lS[r];
        #pragma unroll
        for (int j = 0; j < 4; ++j) {
            int d = tx * 4 + j;
            ctx[(size_t)(b * SEQ + q0 + r) * DMODEL + h * DHEAD + d] = o_acc[i][j] * inv;
        }
    }
}

// ---------------------------------------------------------------------------
// Kernel 3: output projection + bias + residual.  y = ctx @ Wo + bo + x.
// ---------------------------------------------------------------------------
__global__ __launch_bounds__(256) void gemm_oproj_kernel(
    const float* __restrict__ ctx, const float* __restrict__ Wo,
    const float* __restrict__ bo, const float* __restrict__ x,
    float* __restrict__ y)
{
    __shared__ float As[16][68];
    __shared__ float Bs[16][64];

    const int tid = threadIdx.x;
    const int tx = tid & 15, ty = tid >> 4;
    const int m0 = blockIdx.x * 64;
    const int n0 = blockIdx.y * 64;

    float acc[4][4] = {};

    for (int k0 = 0; k0 < DMODEL; k0 += 16) {
        {
            int r = tid >> 4;
            int c = tid & 15;
            #pragma unroll
            for (int i = 0; i < 4; ++i) {
                int row = r + 16 * i;
                As[c][row] = ctx[(size_t)(m0 + row) * DMODEL + k0 + c];
            }
        }
        {
            int c  = tid & 63;
            int r0 = tid >> 6;
            #pragma unroll
            for (int i = 0; i < 4; ++i) {
                int kk = r0 + 4 * i;
                Bs[kk][c] = Wo[(size_t)(k0 + kk) * DMODEL + n0 + c];
            }
        }
        __syncthreads();
        #pragma unroll
        for (int kk = 0; kk < 16; ++kk) {
            float a[4], b[4];
            #pragma unroll
            for (int i = 0; i < 4; ++i) a[i] = As[kk][ty * 4 + i];
            #pragma unroll
            for (int j = 0; j < 4; ++j) b[j] = Bs[kk][tx * 4 + j];
            #pragma unroll
            for (int i = 0; i < 4; ++i)
                #pragma unroll
                for (int j = 0; j < 4; ++j)
                    acc[i][j] += a[i] * b[j];
        }
        __syncthreads();
    }

    #pragma unroll
    for (int i = 0; i < 4; ++i) {
        int t = m0 + ty * 4 + i;
        #pragma unroll
        for (int j = 0; j < 4; ++j) {
            int o = n0 + tx * 4 + j;
            size_t idx = (size_t)t * DMODEL + o;
            y[idx] = acc[i][j] + bo[o] + x[idx];
        }
    }
}

// ---------------------------------------------------------------------------
// Kernel 4: LayerNorm.  One block per token, 256 threads, 3 elems/thread.
// ---------------------------------------------------------------------------
__global__ __launch_bounds__(256) void ln_kernel(
    const float* __restrict__ y, const float* __restrict__ gamma,
    const float* __restrict__ beta, float* __restrict__ out)
{
    const int t   = blockIdx.x;
    const int tid = threadIdx.x;
    const float* row = y + (size_t)t * DMODEL;

    float vals[3];
    float s = 0.f, s2 = 0.f;
    #pragma unroll
    for (int i = 0; i < 3; ++i) {
        float vv = row[tid + 256 * i];
        vals[i] = vv;
        s  += vv;
        s2 += vv * vv;
    }
    #pragma unroll
    for (int off = 32; off > 0; off >>= 1) {
        s  += __shfl_down(s,  off);
        s2 += __shfl_down(s2, off);
    }
    __shared__ float rbuf[8];
    int w = tid >> 6;
    if ((tid & 63) == 0) { rbuf[w] = s; rbuf[4 + w] = s2; }
    __syncthreads();
    float ts  = rbuf[0] + rbuf[1] + rbuf[2] + rbuf[3];
    float ts2 = rbuf[4] + rbuf[5] + rbuf[6] + rbuf[7];
    float mu  = ts * (1.f / DMODEL);
    float var = ts2 * (1.f / DMODEL) - mu * mu;
    float inv = rsqrtf(var + LN_EPS);
    #pragma unroll
    for (int i = 0; i < 3; ++i) {
        int c = tid + 256 * i;
        out[(size_t)t * DMODEL + c] = gamma[c] * (vals[i] - mu) * inv + beta[c];
    }
}

// ---------------------------------------------------------------------------
extern "C" void kernel_launch(void* const* d_in, const int* in_sizes, int n_in,
                              void* d_out, int out_size, void* d_ws, size_t ws_size,
                              hipStream_t stream) {
    const float* x     = (const float*)d_in[0];
    const int*   mask  = (const int*)  d_in[1];
    const float* Wq    = (const float*)d_in[2];
    const float* bq    = (const float*)d_in[3];
    const float* Wk    = (const float*)d_in[4];
    const float* bk    = (const float*)d_in[5];
    const float* Wv    = (const float*)d_in[6];
    const float* bv    = (const float*)d_in[7];
    const float* Wo    = (const float*)d_in[8];
    const float* bo    = (const float*)d_in[9];
    const float* gamma = (const float*)d_in[10];
    const float* beta  = (const float*)d_in[11];
    float* out = (float*)d_out;

    const size_t per = (size_t)NTOK * DMODEL;  // 6,291,456 floats
    float* q = (float*)d_ws;
    float* k = q + per;
    float* v = k + per;
    float* y = q;                 // q dead after attention; reuse for residual sum
    float* ctx = out;             // d_out used as scratch for ctx, overwritten by LN

    dim3 g1(NTOK / 64, DMODEL / 64, 3);
    gemm_qkv_kernel<<<g1, 256, 0, stream>>>(x, Wq, Wk, Wv, bq, bk, bv, q, k, v);

    dim3 g2(SEQ / 64, NH, BATCH);
    attn_kernel<<<g2, 256, 0, stream>>>(q, k, v, mask, ctx);

    dim3 g3(NTOK / 64, DMODEL / 64, 1);
    gemm_oproj_kernel<<<g3, 256, 0, stream>>>(ctx, Wo, bo, x, y);

    ln_kernel<<<NTOK, 256, 0, stream>>>(y, gamma, beta, out);
}

// Round 2
// 451.057 us; speedup vs baseline: 1.9745x; 1.9745x over previous
//
#include <hip/hip_runtime.h>
#include <math.h>

#define NH 12
#define DMODEL 768
#define DHEAD 64
#define BATCH 16
#define SEQ 512
#define NTOK (BATCH*SEQ)   // 8192
#define ATTN_SCALE 0.125f
#define LN_EPS 1e-3f

typedef __attribute__((ext_vector_type(8))) short  bf16x8;
typedef __attribute__((ext_vector_type(8))) unsigned short ushort8;
typedef __attribute__((ext_vector_type(4))) float  f32x4;

__device__ __forceinline__ unsigned short f2bf(float f) {
    unsigned int u = __float_as_uint(f);
    unsigned int r = (u + 0x7fffu + ((u >> 16) & 1u)) >> 16;
    return (unsigned short)r;
}
__device__ __forceinline__ float bf2f(unsigned short h) {
    return __uint_as_float(((unsigned int)h) << 16);
}

__device__ __forceinline__ void async_copy16(const void* g, void* l) {
    __builtin_amdgcn_global_load_lds((const __attribute__((address_space(1))) void*)g,
                                     (__attribute__((address_space(3))) void*)l,
                                     16, 0, 0);
}

// ---------------------------------------------------------------------------
// Prep 1: cast x (fp32) -> xb (bf16), same [NTOK][DMODEL] layout.
// ---------------------------------------------------------------------------
__global__ __launch_bounds__(256) void cast_x_kernel(
    const float* __restrict__ x, unsigned short* __restrict__ xb)
{
    int i = (blockIdx.x * 256 + threadIdx.x) * 4;
    const float4 v = *(const float4*)(x + i);
    unsigned short o0 = f2bf(v.x), o1 = f2bf(v.y), o2 = f2bf(v.z), o3 = f2bf(v.w);
    unsigned long long pack = (unsigned long long)o0 | ((unsigned long long)o1 << 16)
                            | ((unsigned long long)o2 << 32) | ((unsigned long long)o3 << 48);
    *(unsigned long long*)(xb + i) = pack;
}

// ---------------------------------------------------------------------------
// Prep 2: Wt[n][k] = bf16(W[k][n]) for all 4 weight matrices (z index).
// ---------------------------------------------------------------------------
__global__ __launch_bounds__(256) void prep_wt_kernel(
    const float* __restrict__ Wq, const float* __restrict__ Wk,
    const float* __restrict__ Wv, const float* __restrict__ Wo,
    unsigned short* __restrict__ tq, unsigned short* __restrict__ tk,
    unsigned short* __restrict__ tv, unsigned short* __restrict__ to_)
{
    const int zz = blockIdx.z;
    const float* W = (zz == 0) ? Wq : (zz == 1) ? Wk : (zz == 2) ? Wv : Wo;
    unsigned short* T = (zz == 0) ? tq : (zz == 1) ? tk : (zz == 2) ? tv : to_;

    __shared__ float tile[32][33];
    const int bx = blockIdx.x * 32;   // k base
    const int by = blockIdx.y * 32;   // n base
    const int tx = threadIdx.x & 31, ty = threadIdx.x >> 5;   // ty 0..7

    #pragma unroll
    for (int i = 0; i < 32; i += 8)
        tile[ty + i][tx] = W[(size_t)(bx + ty + i) * DMODEL + by + tx];
    __syncthreads();
    #pragma unroll
    for (int i = 0; i < 32; i += 8)
        T[(size_t)(by + ty + i) * DMODEL + bx + tx] = f2bf(tile[tx][ty + i]);
}

// ---------------------------------------------------------------------------
// MFMA GEMM (m97 structure): C[M,N] = A[M,K] @ Wt[N,K]^T, 128x128 tile, BK=32.
// 256 threads = 4 waves in 2x2 grid, each wave 64x64 = 4x4 MFMA 16x16x32 tiles.
// QKV variant: bias add + scatter to [B,H,L,DH] as bf16.
// ---------------------------------------------------------------------------
__global__ __launch_bounds__(256) void mfma_gemm_qkv(
    const unsigned short* __restrict__ xb,
    const unsigned short* __restrict__ wt0, const unsigned short* __restrict__ wt1,
    const unsigned short* __restrict__ wt2,
    const float* __restrict__ b0, const float* __restrict__ b1, const float* __restrict__ b2,
    unsigned short* __restrict__ o0, unsigned short* __restrict__ o1,
    unsigned short* __restrict__ o2)
{
    __shared__ __align__(16) unsigned short As[128 * 32];
    __shared__ __align__(16) unsigned short Bs[128 * 32];

    const int zz = blockIdx.z;
    const unsigned short* Wt = (zz == 0) ? wt0 : (zz == 1) ? wt1 : wt2;
    const float* bias        = (zz == 0) ? b0  : (zz == 1) ? b1  : b2;
    unsigned short* out      = (zz == 0) ? o0  : (zz == 1) ? o1  : o2;

    const int tid  = threadIdx.x;
    const int lane = tid & 63;
    const int w    = tid >> 6;
    const int wm   = w >> 1, wn = w & 1;
    const int m0   = blockIdx.x * 128;
    const int n0   = blockIdx.y * 128;
    const int quad = lane >> 4;
    const int l16  = lane & 15;

    // staging: per wave, A insts {2w,2w+1} and B insts {2w,2w+1}; each inst = 16 rows.
    const int row0 = (2 * w)     * 16 + (lane >> 2);
    const int row1 = (2 * w + 1) * 16 + (lane >> 2);
    const int koff = (lane & 3) * 8;

    f32x4 acc[4][4] = {};

    for (int k0 = 0; k0 < DMODEL; k0 += 32) {
        async_copy16(xb + (size_t)(m0 + row0) * DMODEL + k0 + koff, As + (2 * w)     * 512);
        async_copy16(xb + (size_t)(m0 + row1) * DMODEL + k0 + koff, As + (2 * w + 1) * 512);
        async_copy16(Wt + (size_t)(n0 + row0) * DMODEL + k0 + koff, Bs + (2 * w)     * 512);
        async_copy16(Wt + (size_t)(n0 + row1) * DMODEL + k0 + koff, Bs + (2 * w + 1) * 512);
        __syncthreads();

        bf16x8 a[4], b[4];
        #pragma unroll
        for (int mi = 0; mi < 4; ++mi)
            a[mi] = *(const bf16x8*)&As[(wm * 64 + mi * 16 + l16) * 32 + quad * 8];
        #pragma unroll
        for (int ni = 0; ni < 4; ++ni)
            b[ni] = *(const bf16x8*)&Bs[(wn * 64 + ni * 16 + l16) * 32 + quad * 8];
        #pragma unroll
        for (int mi = 0; mi < 4; ++mi)
            #pragma unroll
            for (int ni = 0; ni < 4; ++ni)
                acc[mi][ni] = __builtin_amdgcn_mfma_f32_16x16x32_bf16(a[mi], b[ni], acc[mi][ni], 0, 0, 0);
        __syncthreads();
    }

    // epilogue: D row = quad*4+r, col = l16 (m89-verified layout)
    #pragma unroll
    for (int ni = 0; ni < 4; ++ni) {
        const int ncol = n0 + wn * 64 + ni * 16 + l16;
        const int h = ncol >> 6, dh = ncol & 63;
        const float bv = bias[ncol];
        #pragma unroll
        for (int mi = 0; mi < 4; ++mi) {
            const int mbase = m0 + wm * 64 + mi * 16 + quad * 4;
            #pragma unroll
            for (int r = 0; r < 4; ++r) {
                const int t = mbase + r;
                const int bi = t >> 9, l = t & 511;
                out[(size_t)((bi * NH + h) * SEQ + l) * DHEAD + dh] = f2bf(acc[mi][ni][r] + bv);
            }
        }
    }
}

// O-proj variant: y = ctx @ Wo + bo + x (fp32 out, contiguous [NTOK][DMODEL]).
__global__ __launch_bounds__(256) void mfma_gemm_oproj(
    const unsigned short* __restrict__ ctxb, const unsigned short* __restrict__ wto,
    const float* __restrict__ bo, const float* __restrict__ x,
    float* __restrict__ y)
{
    __shared__ __align__(16) unsigned short As[128 * 32];
    __shared__ __align__(16) unsigned short Bs[128 * 32];

    const int tid  = threadIdx.x;
    const int lane = tid & 63;
    const int w    = tid >> 6;
    const int wm   = w >> 1, wn = w & 1;
    const int m0   = blockIdx.x * 128;
    const int n0   = blockIdx.y * 128;
    const int quad = lane >> 4;
    const int l16  = lane & 15;

    const int row0 = (2 * w)     * 16 + (lane >> 2);
    const int row1 = (2 * w + 1) * 16 + (lane >> 2);
    const int koff = (lane & 3) * 8;

    f32x4 acc[4][4] = {};

    for (int k0 = 0; k0 < DMODEL; k0 += 32) {
        async_copy16(ctxb + (size_t)(m0 + row0) * DMODEL + k0 + koff, As + (2 * w)     * 512);
        async_copy16(ctxb + (size_t)(m0 + row1) * DMODEL + k0 + koff, As + (2 * w + 1) * 512);
        async_copy16(wto  + (size_t)(n0 + row0) * DMODEL + k0 + koff, Bs + (2 * w)     * 512);
        async_copy16(wto  + (size_t)(n0 + row1) * DMODEL + k0 + koff, Bs + (2 * w + 1) * 512);
        __syncthreads();

        bf16x8 a[4], b[4];
        #pragma unroll
        for (int mi = 0; mi < 4; ++mi)
            a[mi] = *(const bf16x8*)&As[(wm * 64 + mi * 16 + l16) * 32 + quad * 8];
        #pragma unroll
        for (int ni = 0; ni < 4; ++ni)
            b[ni] = *(const bf16x8*)&Bs[(wn * 64 + ni * 16 + l16) * 32 + quad * 8];
        #pragma unroll
        for (int mi = 0; mi < 4; ++mi)
            #pragma unroll
            for (int ni = 0; ni < 4; ++ni)
                acc[mi][ni] = __builtin_amdgcn_mfma_f32_16x16x32_bf16(a[mi], b[ni], acc[mi][ni], 0, 0, 0);
        __syncthreads();
    }

    #pragma unroll
    for (int ni = 0; ni < 4; ++ni) {
        const int ncol = n0 + wn * 64 + ni * 16 + l16;
        const float bv = bo[ncol];
        #pragma unroll
        for (int mi = 0; mi < 4; ++mi) {
            const int mbase = m0 + wm * 64 + mi * 16 + quad * 4;
            #pragma unroll
            for (int r = 0; r < 4; ++r) {
                const size_t idx = (size_t)(mbase + r) * DMODEL + ncol;
                y[idx] = acc[mi][ni][r] + bv + x[idx];
            }
        }
    }
}

// ---------------------------------------------------------------------------
// Flash attention (fp32 VALU math, bf16 I/O). One block per (b,h,64-q tile).
// ---------------------------------------------------------------------------
__global__ __launch_bounds__(256) void attn_kernel(
    const unsigned short* __restrict__ q, const unsigned short* __restrict__ k,
    const unsigned short* __restrict__ v, const int* __restrict__ mask,
    unsigned short* __restrict__ ctxb)
{
    __shared__ float Qs[64][65];
    __shared__ float Ks[64][65];
    __shared__ float Vs[64][65];
    __shared__ float Ps[64][65];
    __shared__ float red[64][17];
    __shared__ float mS[64], lS[64], alphaS[64], maskS[64];

    const int tid = threadIdx.x;
    const int tx = tid & 15, ty = tid >> 4;
    const int q0 = blockIdx.x * 64;
    const int h  = blockIdx.y;
    const int b  = blockIdx.z;

    const unsigned short* qp = q + (size_t)((b * NH + h) * SEQ + q0) * DHEAD;
    const unsigned short* kp = k + (size_t)((b * NH + h) * SEQ) * DHEAD;
    const unsigned short* vp = v + (size_t)((b * NH + h) * SEQ) * DHEAD;

    // load Q tile (64x64): 2 x (256 threads x 8 bf16)
    #pragma unroll
    for (int i = 0; i < 2; ++i) {
        int idx = tid * 8 + 2048 * i;
        int row = idx >> 6, col = idx & 63;
        ushort8 qv = *(const ushort8*)(qp + idx);
        #pragma unroll
        for (int j = 0; j < 8; ++j) Qs[row][col + j] = bf2f(qv[j]);
    }
    if (tid < 64) { mS[tid] = -1e30f; lS[tid] = 0.f; }

    float o_acc[4][4] = {};

    for (int kt = 0; kt < SEQ; kt += 64) {
        __syncthreads();
        #pragma unroll
        for (int i = 0; i < 2; ++i) {
            int idx = tid * 8 + 2048 * i;
            int row = idx >> 6, col = idx & 63;
            ushort8 kv = *(const ushort8*)(kp + (size_t)kt * DHEAD + idx);
            ushort8 vv = *(const ushort8*)(vp + (size_t)kt * DHEAD + idx);
            #pragma unroll
            for (int j = 0; j < 8; ++j) {
                Ks[row][col + j] = bf2f(kv[j]);
                Vs[row][col + j] = bf2f(vv[j]);
            }
        }
        if (tid < 64) maskS[tid] = (mask[b * SEQ + kt + tid] > 0) ? 0.f : -1e9f;
        __syncthreads();

        float s[4][4] = {};
        for (int kk = 0; kk < 64; ++kk) {
            float a[4], bb[4];
            #pragma unroll
            for (int i = 0; i < 4; ++i) a[i] = Qs[ty * 4 + i][kk];
            #pragma unroll
            for (int j = 0; j < 4; ++j) bb[j] = Ks[tx * 4 + j][kk];
            #pragma unroll
            for (int i = 0; i < 4; ++i)
                #pragma unroll
                for (int j = 0; j < 4; ++j)
                    s[i][j] += a[i] * bb[j];
        }
        #pragma unroll
        for (int i = 0; i < 4; ++i)
            #pragma unroll
            for (int j = 0; j < 4; ++j)
                s[i][j] = s[i][j] * ATTN_SCALE + maskS[tx * 4 + j];

        #pragma unroll
        for (int i = 0; i < 4; ++i) {
            float rm = fmaxf(fmaxf(s[i][0], s[i][1]), fmaxf(s[i][2], s[i][3]));
            red[ty * 4 + i][tx] = rm;
        }
        __syncthreads();
        if (tid < 64) {
            float m_old = mS[tid];
            float m_new = m_old;
            #pragma unroll
            for (int t2 = 0; t2 < 16; ++t2) m_new = fmaxf(m_new, red[tid][t2]);
            mS[tid] = m_new;
            alphaS[tid] = __expf(m_old - m_new);
        }
        __syncthreads();

        #pragma unroll
        for (int i = 0; i < 4; ++i) {
            int r = ty * 4 + i;
            float mnew = mS[r];
            float rs = 0.f;
            #pragma unroll
            for (int j = 0; j < 4; ++j) {
                float p = __expf(s[i][j] - mnew);
                Ps[r][tx * 4 + j] = p;
                rs += p;
            }
            red[r][tx] = rs;
        }
        __syncthreads();
        if (tid < 64) {
            float ls = 0.f;
            #pragma unroll
            for (int t2 = 0; t2 < 16; ++t2) ls += red[tid][t2];
            lS[tid] = lS[tid] * alphaS[tid] + ls;
        }

        #pragma unroll
        for (int i = 0; i < 4; ++i) {
            float al = alphaS[ty * 4 + i];
            #pragma unroll
            for (int j = 0; j < 4; ++j) o_acc[i][j] *= al;
        }
        for (int c = 0; c < 64; ++c) {
            float pv[4], vv[4];
            #pragma unroll
            for (int i = 0; i < 4; ++i) pv[i] = Ps[ty * 4 + i][c];
            #pragma unroll
            for (int j = 0; j < 4; ++j) vv[j] = Vs[c][tx * 4 + j];
            #pragma unroll
            for (int i = 0; i < 4; ++i)
                #pragma unroll
                for (int j = 0; j < 4; ++j)
                    o_acc[i][j] += pv[i] * vv[j];
        }
    }
    __syncthreads();

    #pragma unroll
    for (int i = 0; i < 4; ++i) {
        int r = ty * 4 + i;
        float inv = 1.f / lS[r];
        #pragma unroll
        for (int j = 0; j < 4; ++j) {
            int d = tx * 4 + j;
            ctxb[(size_t)(b * SEQ + q0 + r) * DMODEL + h * DHEAD + d] = f2bf(o_acc[i][j] * inv);
        }
    }
}

// ---------------------------------------------------------------------------
// LayerNorm, in-place capable (block reads its whole row before writing).
// ---------------------------------------------------------------------------
__global__ __launch_bounds__(256) void ln_kernel(
    const float* __restrict__ y, const float* __restrict__ gamma,
    const float* __restrict__ beta, float* __restrict__ out)
{
    const int t   = blockIdx.x;
    const int tid = threadIdx.x;
    const float* row = y + (size_t)t * DMODEL;

    float vals[3];
    float s = 0.f, s2 = 0.f;
    #pragma unroll
    for (int i = 0; i < 3; ++i) {
        float vv = row[tid + 256 * i];
        vals[i] = vv;
        s  += vv;
        s2 += vv * vv;
    }
    #pragma unroll
    for (int off = 32; off > 0; off >>= 1) {
        s  += __shfl_down(s,  off);
        s2 += __shfl_down(s2, off);
    }
    __shared__ float rbuf[8];
    int w = tid >> 6;
    if ((tid & 63) == 0) { rbuf[w] = s; rbuf[4 + w] = s2; }
    __syncthreads();
    float ts  = rbuf[0] + rbuf[1] + rbuf[2] + rbuf[3];
    float ts2 = rbuf[4] + rbuf[5] + rbuf[6] + rbuf[7];
    float mu  = ts * (1.f / DMODEL);
    float var = ts2 * (1.f / DMODEL) - mu * mu;
    float inv = rsqrtf(var + LN_EPS);
    #pragma unroll
    for (int i = 0; i < 3; ++i) {
        int c = tid + 256 * i;
        out[(size_t)t * DMODEL + c] = gamma[c] * (vals[i] - mu) * inv + beta[c];
    }
}

// ---------------------------------------------------------------------------
extern "C" void kernel_launch(void* const* d_in, const int* in_sizes, int n_in,
                              void* d_out, int out_size, void* d_ws, size_t ws_size,
                              hipStream_t stream) {
    const float* x     = (const float*)d_in[0];
    const int*   mask  = (const int*)  d_in[1];
    const float* Wq    = (const float*)d_in[2];
    const float* bq    = (const float*)d_in[3];
    const float* Wk    = (const float*)d_in[4];
    const float* bk    = (const float*)d_in[5];
    const float* Wv    = (const float*)d_in[6];
    const float* bv    = (const float*)d_in[7];
    const float* Wo    = (const float*)d_in[8];
    const float* bo    = (const float*)d_in[9];
    const float* gamma = (const float*)d_in[10];
    const float* beta  = (const float*)d_in[11];
    float* out = (float*)d_out;

    const size_t perTok = (size_t)NTOK * DMODEL;   // 6,291,456
    const size_t perW   = (size_t)DMODEL * DMODEL; //   589,824

    unsigned short* xb   = (unsigned short*)d_ws;
    unsigned short* wtq  = xb + perTok;
    unsigned short* wtk  = wtq + perW;
    unsigned short* wtv  = wtk + perW;
    unsigned short* wto  = wtv + perW;
    unsigned short* qb   = wto + perW;
    unsigned short* kb   = qb + perTok;
    unsigned short* vb   = kb + perTok;
    unsigned short* ctxb = vb + perTok;
    float* y = out;   // O-proj output lives in d_out; LN runs in-place

    cast_x_kernel<<<perTok / 1024, 256, 0, stream>>>(x, xb);
    prep_wt_kernel<<<dim3(24, 24, 4), 256, 0, stream>>>(Wq, Wk, Wv, Wo, wtq, wtk, wtv, wto);

    mfma_gemm_qkv<<<dim3(NTOK / 128, DMODEL / 128, 3), 256, 0, stream>>>(
        xb, wtq, wtk, wtv, bq, bk, bv, qb, kb, vb);

    attn_kernel<<<dim3(SEQ / 64, NH, BATCH), 256, 0, stream>>>(qb, kb, vb, mask, ctxb);

    mfma_gemm_oproj<<<dim3(NTOK / 128, DMODEL / 128), 256, 0, stream>>>(
        ctxb, wto, bo, x, y);

    ln_kernel<<<NTOK, 256, 0, stream>>>(y, gamma, beta, out);
}

// Round 3
// 237.203 us; speedup vs baseline: 3.7546x; 1.9016x over previous
//
#include <hip/hip_runtime.h>
#include <math.h>

#define NH 12
#define DMODEL 768
#define DHEAD 64
#define BATCH 16
#define SEQ 512
#define NTOK (BATCH*SEQ)   // 8192
#define ATTN_SCALE 0.125f
#define LN_EPS 1e-3f
#define PADB 72            // padded LDS row length (bf16) for 64-wide tiles

typedef __attribute__((ext_vector_type(8))) short  bf16x8;
typedef __attribute__((ext_vector_type(8))) unsigned short ushort8;
typedef __attribute__((ext_vector_type(4))) float  f32x4;

__device__ __forceinline__ unsigned short f2bf(float f) {
    unsigned int u = __float_as_uint(f);
    unsigned int r = (u + 0x7fffu + ((u >> 16) & 1u)) >> 16;
    return (unsigned short)r;
}
__device__ __forceinline__ float bf2f(unsigned short h) {
    return __uint_as_float(((unsigned int)h) << 16);
}

__device__ __forceinline__ void async_copy16(const void* g, void* l) {
    __builtin_amdgcn_global_load_lds((const __attribute__((address_space(1))) void*)g,
                                     (__attribute__((address_space(3))) void*)l,
                                     16, 0, 0);
}

// ---------------------------------------------------------------------------
// Prep 1: cast x (fp32) -> xb (bf16), same [NTOK][DMODEL] layout.
// ---------------------------------------------------------------------------
__global__ __launch_bounds__(256) void cast_x_kernel(
    const float* __restrict__ x, unsigned short* __restrict__ xb)
{
    int i = (blockIdx.x * 256 + threadIdx.x) * 4;
    const float4 v = *(const float4*)(x + i);
    unsigned short o0 = f2bf(v.x), o1 = f2bf(v.y), o2 = f2bf(v.z), o3 = f2bf(v.w);
    unsigned long long pack = (unsigned long long)o0 | ((unsigned long long)o1 << 16)
                            | ((unsigned long long)o2 << 32) | ((unsigned long long)o3 << 48);
    *(unsigned long long*)(xb + i) = pack;
}

// ---------------------------------------------------------------------------
// Prep 2: Wt[n][k] = bf16(W[k][n]) for all 4 weight matrices (z index).
// ---------------------------------------------------------------------------
__global__ __launch_bounds__(256) void prep_wt_kernel(
    const float* __restrict__ Wq, const float* __restrict__ Wk,
    const float* __restrict__ Wv, const float* __restrict__ Wo,
    unsigned short* __restrict__ tq, unsigned short* __restrict__ tk,
    unsigned short* __restrict__ tv, unsigned short* __restrict__ to_)
{
    const int zz = blockIdx.z;
    const float* W = (zz == 0) ? Wq : (zz == 1) ? Wk : (zz == 2) ? Wv : Wo;
    unsigned short* T = (zz == 0) ? tq : (zz == 1) ? tk : (zz == 2) ? tv : to_;

    __shared__ float tile[32][33];
    const int bx = blockIdx.x * 32;   // k base
    const int by = blockIdx.y * 32;   // n base
    const int tx = threadIdx.x & 31, ty = threadIdx.x >> 5;   // ty 0..7

    #pragma unroll
    for (int i = 0; i < 32; i += 8)
        tile[ty + i][tx] = W[(size_t)(bx + ty + i) * DMODEL + by + tx];
    __syncthreads();
    #pragma unroll
    for (int i = 0; i < 32; i += 8)
        T[(size_t)(by + ty + i) * DMODEL + bx + tx] = f2bf(tile[tx][ty + i]);
}

// ---------------------------------------------------------------------------
// MFMA GEMM (m97 structure): C[M,N] = A[M,K] @ Wt[N,K]^T, 128x128 tile, BK=32.
// QKV variant: bias add; Q,K scatter to [B,H,L,DH]; V scatter TRANSPOSED to
// [B,H,DH,SEQ] (packed 8B stores) so attention's PV B-frags are contiguous.
// ---------------------------------------------------------------------------
__global__ __launch_bounds__(256) void mfma_gemm_qkv(
    const unsigned short* __restrict__ xb,
    const unsigned short* __restrict__ wt0, const unsigned short* __restrict__ wt1,
    const unsigned short* __restrict__ wt2,
    const float* __restrict__ b0, const float* __restrict__ b1, const float* __restrict__ b2,
    unsigned short* __restrict__ o0, unsigned short* __restrict__ o1,
    unsigned short* __restrict__ o2)
{
    __shared__ __align__(16) unsigned short As[128 * 32];
    __shared__ __align__(16) unsigned short Bs[128 * 32];

    const int zz = blockIdx.z;
    const unsigned short* Wt = (zz == 0) ? wt0 : (zz == 1) ? wt1 : wt2;
    const float* bias        = (zz == 0) ? b0  : (zz == 1) ? b1  : b2;
    unsigned short* out      = (zz == 0) ? o0  : (zz == 1) ? o1  : o2;

    const int tid  = threadIdx.x;
    const int lane = tid & 63;
    const int w    = tid >> 6;
    const int wm   = w >> 1, wn = w & 1;
    const int m0   = blockIdx.x * 128;
    const int n0   = blockIdx.y * 128;
    const int quad = lane >> 4;
    const int l16  = lane & 15;

    const int row0 = (2 * w)     * 16 + (lane >> 2);
    const int row1 = (2 * w + 1) * 16 + (lane >> 2);
    const int koff = (lane & 3) * 8;

    f32x4 acc[4][4] = {};

    for (int k0 = 0; k0 < DMODEL; k0 += 32) {
        async_copy16(xb + (size_t)(m0 + row0) * DMODEL + k0 + koff, As + (2 * w)     * 512);
        async_copy16(xb + (size_t)(m0 + row1) * DMODEL + k0 + koff, As + (2 * w + 1) * 512);
        async_copy16(Wt + (size_t)(n0 + row0) * DMODEL + k0 + koff, Bs + (2 * w)     * 512);
        async_copy16(Wt + (size_t)(n0 + row1) * DMODEL + k0 + koff, Bs + (2 * w + 1) * 512);
        __syncthreads();

        bf16x8 a[4], b[4];
        #pragma unroll
        for (int mi = 0; mi < 4; ++mi)
            a[mi] = *(const bf16x8*)&As[(wm * 64 + mi * 16 + l16) * 32 + quad * 8];
        #pragma unroll
        for (int ni = 0; ni < 4; ++ni)
            b[ni] = *(const bf16x8*)&Bs[(wn * 64 + ni * 16 + l16) * 32 + quad * 8];
        #pragma unroll
        for (int mi = 0; mi < 4; ++mi)
            #pragma unroll
            for (int ni = 0; ni < 4; ++ni)
                acc[mi][ni] = __builtin_amdgcn_mfma_f32_16x16x32_bf16(a[mi], b[ni], acc[mi][ni], 0, 0, 0);
        __syncthreads();
    }

    if (zz == 2) {
        // V: write transposed [B,H,DH,SEQ]; 4 consecutive tokens pack to 8B.
        #pragma unroll
        for (int ni = 0; ni < 4; ++ni) {
            const int ncol = n0 + wn * 64 + ni * 16 + l16;
            const int h = ncol >> 6, dh = ncol & 63;
            const float bv = bias[ncol];
            #pragma unroll
            for (int mi = 0; mi < 4; ++mi) {
                const int mbase = m0 + wm * 64 + mi * 16 + quad * 4;
                const int bi = mbase >> 9, l = mbase & 511;
                unsigned long long pack = 0;
                #pragma unroll
                for (int r = 0; r < 4; ++r)
                    pack |= (unsigned long long)f2bf(acc[mi][ni][r] + bv) << (16 * r);
                *(unsigned long long*)(out + ((size_t)((bi * NH + h) * DHEAD + dh)) * SEQ + l) = pack;
            }
        }
    } else {
        #pragma unroll
        for (int ni = 0; ni < 4; ++ni) {
            const int ncol = n0 + wn * 64 + ni * 16 + l16;
            const int h = ncol >> 6, dh = ncol & 63;
            const float bv = bias[ncol];
            #pragma unroll
            for (int mi = 0; mi < 4; ++mi) {
                const int mbase = m0 + wm * 64 + mi * 16 + quad * 4;
                #pragma unroll
                for (int r = 0; r < 4; ++r) {
                    const int t = mbase + r;
                    const int bi = t >> 9, l = t & 511;
                    out[(size_t)((bi * NH + h) * SEQ + l) * DHEAD + dh] = f2bf(acc[mi][ni][r] + bv);
                }
            }
        }
    }
}

// O-proj variant: y = ctx @ Wo + bo + x (fp32 out, contiguous [NTOK][DMODEL]).
__global__ __launch_bounds__(256) void mfma_gemm_oproj(
    const unsigned short* __restrict__ ctxb, const unsigned short* __restrict__ wto,
    const float* __restrict__ bo, const float* __restrict__ x,
    float* __restrict__ y)
{
    __shared__ __align__(16) unsigned short As[128 * 32];
    __shared__ __align__(16) unsigned short Bs[128 * 32];

    const int tid  = threadIdx.x;
    const int lane = tid & 63;
    const int w    = tid >> 6;
    const int wm   = w >> 1, wn = w & 1;
    const int m0   = blockIdx.x * 128;
    const int n0   = blockIdx.y * 128;
    const int quad = lane >> 4;
    const int l16  = lane & 15;

    const int row0 = (2 * w)     * 16 + (lane >> 2);
    const int row1 = (2 * w + 1) * 16 + (lane >> 2);
    const int koff = (lane & 3) * 8;

    f32x4 acc[4][4] = {};

    for (int k0 = 0; k0 < DMODEL; k0 += 32) {
        async_copy16(ctxb + (size_t)(m0 + row0) * DMODEL + k0 + koff, As + (2 * w)     * 512);
        async_copy16(ctxb + (size_t)(m0 + row1) * DMODEL + k0 + koff, As + (2 * w + 1) * 512);
        async_copy16(wto  + (size_t)(n0 + row0) * DMODEL + k0 + koff, Bs + (2 * w)     * 512);
        async_copy16(wto  + (size_t)(n0 + row1) * DMODEL + k0 + koff, Bs + (2 * w + 1) * 512);
        __syncthreads();

        bf16x8 a[4], b[4];
        #pragma unroll
        for (int mi = 0; mi < 4; ++mi)
            a[mi] = *(const bf16x8*)&As[(wm * 64 + mi * 16 + l16) * 32 + quad * 8];
        #pragma unroll
        for (int ni = 0; ni < 4; ++ni)
            b[ni] = *(const bf16x8*)&Bs[(wn * 64 + ni * 16 + l16) * 32 + quad * 8];
        #pragma unroll
        for (int mi = 0; mi < 4; ++mi)
            #pragma unroll
            for (int ni = 0; ni < 4; ++ni)
                acc[mi][ni] = __builtin_amdgcn_mfma_f32_16x16x32_bf16(a[mi], b[ni], acc[mi][ni], 0, 0, 0);
        __syncthreads();
    }

    #pragma unroll
    for (int ni = 0; ni < 4; ++ni) {
        const int ncol = n0 + wn * 64 + ni * 16 + l16;
        const float bv = bo[ncol];
        #pragma unroll
        for (int mi = 0; mi < 4; ++mi) {
            const int mbase = m0 + wm * 64 + mi * 16 + quad * 4;
            #pragma unroll
            for (int r = 0; r < 4; ++r) {
                const size_t idx = (size_t)(mbase + r) * DMODEL + ncol;
                y[idx] = acc[mi][ni][r] + bv + x[idx];
            }
        }
    }
}

// ---------------------------------------------------------------------------
// MFMA flash attention. Block = (b, h, 128-query tile); 4 waves x 32 q-rows.
// K-tiles of 64. S=Q·K^T via mfma; P -> LDS round-trip (C-layout -> A-layout);
// row sums via ones-MFMA; V pre-transposed globally to [B,H,DH,SEQ].
// ---------------------------------------------------------------------------
__global__ __launch_bounds__(256) void attn_mfma_kernel(
    const unsigned short* __restrict__ q, const unsigned short* __restrict__ k,
    const unsigned short* __restrict__ vt, const int* __restrict__ mask,
    unsigned short* __restrict__ ctxb)
{
    __shared__ __align__(16) unsigned short Ks[64 * PADB];
    __shared__ __align__(16) unsigned short Vs[64 * PADB];   // V^T tile: [d][key]
    __shared__ __align__(16) unsigned short QP[128 * PADB];  // Q staging, then P
    __shared__ float maskF[64];

    const int tid  = threadIdx.x;
    const int lane = tid & 63;
    const int w    = tid >> 6;
    const int quad = lane >> 4;
    const int l16  = lane & 15;
    const int q0   = blockIdx.x * 128;
    const int h    = blockIdx.y;
    const int b    = blockIdx.z;

    const unsigned short* qp  = q  + ((size_t)(b * NH + h) * SEQ + q0) * DHEAD;
    const unsigned short* kp  = k  + (size_t)(b * NH + h) * SEQ * DHEAD;
    const unsigned short* vtp = vt + (size_t)(b * NH + h) * DHEAD * SEQ;

    // stage Q tile (128x64) into QP
    #pragma unroll
    for (int i = 0; i < 4; ++i) {
        int idx = tid * 8 + 2048 * i;
        *(ushort8*)&QP[(idx >> 6) * PADB + (idx & 63)] = *(const ushort8*)(qp + idx);
    }
    __syncthreads();

    bf16x8 aQ[2][2];
    #pragma unroll
    for (int mi = 0; mi < 2; ++mi)
        #pragma unroll
        for (int kb = 0; kb < 2; ++kb)
            aQ[mi][kb] = *(const bf16x8*)&QP[(w * 32 + mi * 16 + l16) * PADB + kb * 32 + quad * 8];

    bf16x8 ones;
    #pragma unroll
    for (int j = 0; j < 8; ++j) ones[j] = (short)0x3F80;   // bf16 1.0

    float m_st[2][4], l_st[2][4];
    #pragma unroll
    for (int mi = 0; mi < 2; ++mi)
        #pragma unroll
        for (int r = 0; r < 4; ++r) { m_st[mi][r] = -1e30f; l_st[mi][r] = 0.f; }
    f32x4 o[2][4] = {};
    const f32x4 zf = {0.f, 0.f, 0.f, 0.f};

    for (int kt = 0; kt < SEQ; kt += 64) {
        __syncthreads();   // prior iter's Ks/Vs reads (and first-iter aQ) done
        #pragma unroll
        for (int i = 0; i < 2; ++i) {
            int idx = tid * 8 + 2048 * i;
            int r = idx >> 6, c = idx & 63;
            *(ushort8*)&Ks[r * PADB + c] = *(const ushort8*)(kp + (size_t)kt * DHEAD + idx);
            *(ushort8*)&Vs[r * PADB + c] = *(const ushort8*)(vtp + (size_t)r * SEQ + kt + c);
        }
        if (tid < 64) maskF[tid] = (mask[b * SEQ + kt + tid] > 0) ? 0.f : -1e9f;
        __syncthreads();

        // S = Q·K^T  (C-layout: row=quad*4+r (query), col=l16 (key))
        f32x4 s[2][4];
        float mk[4];
        #pragma unroll
        for (int ni = 0; ni < 4; ++ni) {
            bf16x8 bK0 = *(const bf16x8*)&Ks[(ni * 16 + l16) * PADB + quad * 8];
            bf16x8 bK1 = *(const bf16x8*)&Ks[(ni * 16 + l16) * PADB + 32 + quad * 8];
            mk[ni] = maskF[ni * 16 + l16];
            #pragma unroll
            for (int mi = 0; mi < 2; ++mi) {
                f32x4 t0 = __builtin_amdgcn_mfma_f32_16x16x32_bf16(aQ[mi][0], bK0, zf, 0, 0, 0);
                s[mi][ni] = __builtin_amdgcn_mfma_f32_16x16x32_bf16(aQ[mi][1], bK1, t0, 0, 0, 0);
            }
        }

        // scale + mask; row max over 16 lanes (same quad) + online rescale
        float alpha[2][4];
        #pragma unroll
        for (int mi = 0; mi < 2; ++mi) {
            #pragma unroll
            for (int r = 0; r < 4; ++r) {
                float mx = -3e38f;
                #pragma unroll
                for (int ni = 0; ni < 4; ++ni) {
                    float sv = s[mi][ni][r] * ATTN_SCALE + mk[ni];
                    s[mi][ni][r] = sv;
                    mx = fmaxf(mx, sv);
                }
                mx = fmaxf(mx, __shfl_xor(mx, 1));
                mx = fmaxf(mx, __shfl_xor(mx, 2));
                mx = fmaxf(mx, __shfl_xor(mx, 4));
                mx = fmaxf(mx, __shfl_xor(mx, 8));
                float mo = m_st[mi][r];
                float mn = fmaxf(mo, mx);
                float al = __expf(mo - mn);
                m_st[mi][r] = mn;
                l_st[mi][r] *= al;
                alpha[mi][r] = al;
            }
        }

        // P = exp(S - m) -> LDS (C-layout write), rescale O
        #pragma unroll
        for (int mi = 0; mi < 2; ++mi)
            #pragma unroll
            for (int ni = 0; ni < 4; ++ni)
                #pragma unroll
                for (int r = 0; r < 4; ++r)
                    QP[(w * 32 + mi * 16 + quad * 4 + r) * PADB + ni * 16 + l16]
                        = f2bf(__expf(s[mi][ni][r] - m_st[mi][r]));
        #pragma unroll
        for (int mi = 0; mi < 2; ++mi)
            #pragma unroll
            for (int ni = 0; ni < 4; ++ni)
                #pragma unroll
                for (int r = 0; r < 4; ++r)
                    o[mi][ni][r] *= alpha[mi][r];

        // P back as A-frags (per-wave region; wave-internal LDS ordering)
        bf16x8 aP[2][2];
        #pragma unroll
        for (int mi = 0; mi < 2; ++mi)
            #pragma unroll
            for (int kb = 0; kb < 2; ++kb)
                aP[mi][kb] = *(const bf16x8*)&QP[(w * 32 + mi * 16 + l16) * PADB + kb * 32 + quad * 8];

        // row sums via ones-MFMA (replicated across cols in C-layout)
        f32x4 rs[2];
        #pragma unroll
        for (int mi = 0; mi < 2; ++mi) {
            f32x4 t0 = __builtin_amdgcn_mfma_f32_16x16x32_bf16(aP[mi][0], ones, zf, 0, 0, 0);
            rs[mi] = __builtin_amdgcn_mfma_f32_16x16x32_bf16(aP[mi][1], ones, t0, 0, 0, 0);
        }

        // O += P · V   (B-frag: n=d (row of Vs), k=key (contiguous))
        #pragma unroll
        for (int ni = 0; ni < 4; ++ni) {
            bf16x8 bV0 = *(const bf16x8*)&Vs[(ni * 16 + l16) * PADB + quad * 8];
            bf16x8 bV1 = *(const bf16x8*)&Vs[(ni * 16 + l16) * PADB + 32 + quad * 8];
            #pragma unroll
            for (int mi = 0; mi < 2; ++mi) {
                o[mi][ni] = __builtin_amdgcn_mfma_f32_16x16x32_bf16(aP[mi][0], bV0, o[mi][ni], 0, 0, 0);
                o[mi][ni] = __builtin_amdgcn_mfma_f32_16x16x32_bf16(aP[mi][1], bV1, o[mi][ni], 0, 0, 0);
            }
        }
        #pragma unroll
        for (int mi = 0; mi < 2; ++mi)
            #pragma unroll
            for (int r = 0; r < 4; ++r)
                l_st[mi][r] += rs[mi][r];
    }

    // epilogue: ctx[b, tok, h*64 + d] = O / l
    #pragma unroll
    for (int mi = 0; mi < 2; ++mi)
        #pragma unroll
        for (int r = 0; r < 4; ++r) {
            float inv = 1.f / l_st[mi][r];
            int tok = q0 + w * 32 + mi * 16 + quad * 4 + r;
            #pragma unroll
            for (int ni = 0; ni < 4; ++ni)
                ctxb[(size_t)(b * SEQ + tok) * DMODEL + h * DHEAD + ni * 16 + l16]
                    = f2bf(o[mi][ni][r] * inv);
        }
}

// ---------------------------------------------------------------------------
// LayerNorm, in-place capable (block reads its whole row before writing).
// ---------------------------------------------------------------------------
__global__ __launch_bounds__(256) void ln_kernel(
    const float* __restrict__ y, const float* __restrict__ gamma,
    const float* __restrict__ beta, float* __restrict__ out)
{
    const int t   = blockIdx.x;
    const int tid = threadIdx.x;
    const float* row = y + (size_t)t * DMODEL;

    float vals[3];
    float s = 0.f, s2 = 0.f;
    #pragma unroll
    for (int i = 0; i < 3; ++i) {
        float vv = row[tid + 256 * i];
        vals[i] = vv;
        s  += vv;
        s2 += vv * vv;
    }
    #pragma unroll
    for (int off = 32; off > 0; off >>= 1) {
        s  += __shfl_down(s,  off);
        s2 += __shfl_down(s2, off);
    }
    __shared__ float rbuf[8];
    int w = tid >> 6;
    if ((tid & 63) == 0) { rbuf[w] = s; rbuf[4 + w] = s2; }
    __syncthreads();
    float ts  = rbuf[0] + rbuf[1] + rbuf[2] + rbuf[3];
    float ts2 = rbuf[4] + rbuf[5] + rbuf[6] + rbuf[7];
    float mu  = ts * (1.f / DMODEL);
    float var = ts2 * (1.f / DMODEL) - mu * mu;
    float inv = rsqrtf(var + LN_EPS);
    #pragma unroll
    for (int i = 0; i < 3; ++i) {
        int c = tid + 256 * i;
        out[(size_t)t * DMODEL + c] = gamma[c] * (vals[i] - mu) * inv + beta[c];
    }
}

// ---------------------------------------------------------------------------
extern "C" void kernel_launch(void* const* d_in, const int* in_sizes, int n_in,
                              void* d_out, int out_size, void* d_ws, size_t ws_size,
                              hipStream_t stream) {
    const float* x     = (const float*)d_in[0];
    const int*   mask  = (const int*)  d_in[1];
    const float* Wq    = (const float*)d_in[2];
    const float* bq    = (const float*)d_in[3];
    const float* Wk    = (const float*)d_in[4];
    const float* bk    = (const float*)d_in[5];
    const float* Wv    = (const float*)d_in[6];
    const float* bv    = (const float*)d_in[7];
    const float* Wo    = (const float*)d_in[8];
    const float* bo    = (const float*)d_in[9];
    const float* gamma = (const float*)d_in[10];
    const float* beta  = (const float*)d_in[11];
    float* out = (float*)d_out;

    const size_t perTok = (size_t)NTOK * DMODEL;   // 6,291,456
    const size_t perW   = (size_t)DMODEL * DMODEL; //   589,824

    unsigned short* xb   = (unsigned short*)d_ws;
    unsigned short* wtq  = xb + perTok;
    unsigned short* wtk  = wtq + perW;
    unsigned short* wtv  = wtk + perW;
    unsigned short* wto  = wtv + perW;
    unsigned short* qb   = wto + perW;
    unsigned short* kb   = qb + perTok;
    unsigned short* vb   = kb + perTok;    // holds V^T: [B,H,DH,SEQ]
    unsigned short* ctxb = vb + perTok;
    float* y = out;   // O-proj output lives in d_out; LN runs in-place

    cast_x_kernel<<<perTok / 1024, 256, 0, stream>>>(x, xb);
    prep_wt_kernel<<<dim3(24, 24, 4), 256, 0, stream>>>(Wq, Wk, Wv, Wo, wtq, wtk, wtv, wto);

    mfma_gemm_qkv<<<dim3(NTOK / 128, DMODEL / 128, 3), 256, 0, stream>>>(
        xb, wtq, wtk, wtv, bq, bk, bv, qb, kb, vb);

    attn_mfma_kernel<<<dim3(SEQ / 128, NH, BATCH), 256, 0, stream>>>(qb, kb, vb, mask, ctxb);

    mfma_gemm_oproj<<<dim3(NTOK / 128, DMODEL / 128), 256, 0, stream>>>(
        ctxb, wto, bo, x, y);

    ln_kernel<<<NTOK, 256, 0, stream>>>(y, gamma, beta, out);
}